// Round 9
// baseline (722.849 us; speedup 1.0000x reference)
//
#include <hip/hip_runtime.h>

#define NT 4096          // time samples per column
#define NCOL 4096        // 512 traces * 8 channels
#define EPT 64           // elements per lane: one wave sorts one whole column
#define BLOCK 512        // 8 waves: waves 0-3 pred cols w, waves 4-7 obs cols w
#define NBLOCKS 1024     // 4096 cols / 4 cols per block

__device__ __forceinline__ float b2f(int i) { return __builtin_bit_cast(float, i); }
__device__ __forceinline__ int   f2b(float f) { return __builtin_bit_cast(int, f); }

// Cross-lane fetch of partner lane^XM's value (full exec always).
// XM 1,2,3 (quad_perm), 7 (row_half_mirror), 8 (row_ror:8), 15 (row_mirror): DPP,
// VALU pipe, zero DS traffic. XM 4,16,31: ds_swizzle. XM 63: ds_bpermute.
template <int XM>
__device__ __forceinline__ float lx(float v) {
    const int i = f2b(v);
    int r;
    if constexpr (XM == 1)       r = __builtin_amdgcn_update_dpp(0, i, 0xB1,  0xF, 0xF, true);
    else if constexpr (XM == 2)  r = __builtin_amdgcn_update_dpp(0, i, 0x4E,  0xF, 0xF, true);
    else if constexpr (XM == 3)  r = __builtin_amdgcn_update_dpp(0, i, 0x1B,  0xF, 0xF, true);
    else if constexpr (XM == 7)  r = __builtin_amdgcn_update_dpp(0, i, 0x141, 0xF, 0xF, true);
    else if constexpr (XM == 8)  r = __builtin_amdgcn_update_dpp(0, i, 0x128, 0xF, 0xF, true);
    else if constexpr (XM == 15) r = __builtin_amdgcn_update_dpp(0, i, 0x140, 0xF, 0xF, true);
    else if constexpr (XM == 4)  r = __builtin_amdgcn_ds_swizzle(i, 0x101F);
    else if constexpr (XM == 16) r = __builtin_amdgcn_ds_swizzle(i, 0x401F);
    else if constexpr (XM == 31) r = __builtin_amdgcn_ds_swizzle(i, 0x7C1F);
    else {
        const int lane = (int)(threadIdx.x & 63);
        r = __builtin_amdgcn_ds_bpermute((lane ^ XM) << 2, i);
    }
    return b2f(r);
}

__device__ __forceinline__ void cemin(float& a, float& b) {
    const float lo = fminf(a, b);
    const float hi = fmaxf(a, b);
    a = lo; b = hi;
}
__device__ __forceinline__ float csel(float x, float y, bool keep_min) {
    return ((x < y) == keep_min) ? x : y;
}

// ---- stage bodies: each instantiated ONCE; runtime switches select them.
// Inside every body the x[] indices are compile-time constants (rule-#20 safe);
// the runtime stage variables only choose WHICH body runs.

// intra-lane reversal stage of merge size KK
template <int KK>
__device__ __forceinline__ void revi(float (&x)[EPT]) {
    #pragma unroll
    for (int base = 0; base < EPT; base += KK)
        #pragma unroll
        for (int o = 0; o < KK / 2; ++o)
            cemin(x[base + o], x[base + KK - 1 - o]);
}

// intra-lane plain stage, element-xor J
template <int J>
__device__ __forceinline__ void plaini(float (&x)[EPT]) {
    #pragma unroll
    for (int e = 0; e < EPT; ++e)
        if ((e & J) == 0) cemin(x[e], x[e | J]);
}

// cross-lane plain stage, lane-xor M, same element index
template <int M>
__device__ __forceinline__ void plain_stage(float (&x)[EPT], int L) {
    const bool km = (L & M) == 0;
    #pragma unroll
    for (int e = 0; e < EPT; ++e) {
        const float y = lx<M>(x[e]);
        x[e] = csel(x[e], y, km);
    }
}

// cross-lane reversal of merge k = 64*K: partner lane L^(K-1), element mirror
// e<->63-e, keep-min if (L & K/2)==0
template <int K>
__device__ __forceinline__ void rev_cross(float (&x)[EPT], int L) {
    const bool km = (L & (K >> 1)) == 0;
    #pragma unroll
    for (int e = 0; e < EPT / 2; ++e) {
        const float ylo = lx<K - 1>(x[EPT - 1 - e]);   // partner's mirrored element
        const float yhi = lx<K - 1>(x[e]);
        x[e]           = csel(x[e], ylo, km);
        x[EPT - 1 - e] = csel(x[EPT - 1 - e], yhi, km);
    }
}

// intra-thread plain stages j = 32..1, all ascending (normalized network)
__device__ __forceinline__ void tail32(float (&x)[EPT]) {
    #pragma unroll
    for (int j = 32; j >= 1; j >>= 1) {
        #pragma unroll
        for (int e = 0; e < EPT; ++e)
            if ((e & j) == 0) cemin(x[e], x[e | j]);
    }
}

// LDS (one union, phases sequential):
//   staging: 2 halves x 4 cols x 1024-word chunk regions = 8192 words (32 KB)
//   epilogue strips: 4 cols x 64 lanes x 33 words        = 8448 words (33 KB)
#define LS_WORDS 8448

__global__ __launch_bounds__(512, 4) void wass_kernel(const float* __restrict__ pred,
                                                      const float* __restrict__ obs,
                                                      float* __restrict__ out) {
    __shared__ __align__(16) float ls[LS_WORDS];

    const int bid  = blockIdx.x;
    const int cb   = (bid & 7) * 128 + (bid >> 3);   // XCD-band col-block swizzle
    const int col0 = cb * 4;

    const int t    = threadIdx.x;
    const int half = t >> 8;           // 0 = pred, 1 = obs
    const int ht   = t & 255;          // thread within half
    const int w    = (t >> 6) & 3;     // column (0..3) this wave sorts
    const int L    = t & 63;           // lane

    const float* __restrict__ src = half ? obs : pred;

    // ---- staged load + transpose: 4 chunks of 1024 rows (R4-verified) ----
    // Per (half, col): 1024-word region, word(lr) = (lr&~31)|((lr&31)^((lr>>5)&15)).
    // Writer thread ht owns lr = 4*ht+j; reader lane L reads lr = L*16+s.
    // Both are exactly 2-way bank aliased = free. (q stays unrolled: x[q*16+s]
    // must be a static index.)
    float x[EPT];
    {
        float* stg = ls + half * 4096;
        #pragma unroll
        for (int q = 0; q < 4; ++q) {
            #pragma unroll
            for (int j = 0; j < 4; ++j) {
                const int lr = (ht << 2) | j;                      // 0..1023
                const int r  = (lr >> 4) * 64 + q * 16 + (lr & 15);
                const float4 v = *(const float4*)&src[(size_t)r * NCOL + col0];
                const int wd = (lr & ~31) | ((lr & 31) ^ ((lr >> 5) & 15));
                stg[wd]        = v.x;      // column col0
                stg[1024 + wd] = v.y;      // column col0+1
                stg[2048 + wd] = v.z;      // column col0+2
                stg[3072 + wd] = v.w;      // column col0+3
            }
            __syncthreads();
            #pragma unroll
            for (int s = 0; s < 16; ++s) {
                const int lr = L * 16 + s;
                const int wd = (lr & ~31) | ((lr & 31) ^ ((lr >> 5) & 15));
                x[q * 16 + s] = stg[w * 1024 + wd];
            }
            __syncthreads();
        }
    }

    // ---- phase 1: normalized bitonic sort of my 64 contiguous elements ----
    // ROLLED: each stage body exists once; k/j are runtime (opaque to the
    // optimizer) so the schedule is a loop, not 25 KB of straight-line code.
    {
        int nk = 6;
        asm volatile("" : "+s"(nk));
        int k = 2;
        #pragma clang loop unroll(disable)
        for (int ik = 0; ik < nk; ++ik) {
            asm volatile("" : "+s"(k));
            switch (k) {
                case 2:  revi<2>(x);  break;
                case 4:  revi<4>(x);  break;
                case 8:  revi<8>(x);  break;
                case 16: revi<16>(x); break;
                case 32: revi<32>(x); break;
                default: revi<64>(x); break;
            }
            int j = k >> 2;
            #pragma clang loop unroll(disable)
            while (j >= 1) {
                asm volatile("" : "+s"(j));
                switch (j) {
                    case 16: plaini<16>(x); break;
                    case 8:  plaini<8>(x);  break;
                    case 4:  plaini<4>(x);  break;
                    case 2:  plaini<2>(x);  break;
                    default: plaini<1>(x);  break;
                }
                j >>= 1;
            }
            k <<= 1;
        }
    }

    // ---- phase 2: merges k = 128..4096, all in-wave, no barriers ----
    // ROLLED the same way: rev_cross<K> + plain_stage<M> chain + tail32.
    {
        int nK = 6;
        asm volatile("" : "+s"(nK));
        int K = 2;
        #pragma clang loop unroll(disable)
        for (int iK = 0; iK < nK; ++iK) {
            asm volatile("" : "+s"(K));
            switch (K) {
                case 2:  rev_cross<2>(x, L);  break;
                case 4:  rev_cross<4>(x, L);  break;
                case 8:  rev_cross<8>(x, L);  break;
                case 16: rev_cross<16>(x, L); break;
                case 32: rev_cross<32>(x, L); break;
                default: rev_cross<64>(x, L); break;
            }
            int M = K >> 2;
            #pragma clang loop unroll(disable)
            while (M >= 1) {
                asm volatile("" : "+s"(M));
                switch (M) {
                    case 16: plain_stage<16>(x, L); break;
                    case 8:  plain_stage<8>(x, L);  break;
                    case 4:  plain_stage<4>(x, L);  break;
                    case 2:  plain_stage<2>(x, L);  break;
                    default: plain_stage<1>(x, L);  break;
                }
                M >>= 1;
            }
            tail32(x);
            K <<= 1;
        }
    }

    // ---- epilogue: two 32-element passes, scalar stride-33 strips.
    // bank = (L+e)&31 for both write and read: 2-way, free. (hh static.) ----
    __syncthreads();                   // staging region is dead; safe to reuse
    const int sb = (w * 64 + L) * 33;
    float s = 0.0f;
    #pragma unroll
    for (int hh = 0; hh < 2; ++hh) {
        if (half == 0) {
            #pragma unroll
            for (int e = 0; e < 32; ++e)
                ls[sb + e] = x[hh * 32 + e];
        }
        __syncthreads();
        if (half == 1) {
            #pragma unroll
            for (int e = 0; e < 32; ++e)
                s += fabsf(x[hh * 32 + e] - ls[sb + e]);
        }
        __syncthreads();
    }
    if (half == 1) {
        #pragma unroll
        for (int off = 32; off > 0; off >>= 1)
            s += __shfl_down(s, off, 64);
        if (L == 0)
            atomicAdd(out, s * (1.0f / ((float)NT * (float)NCOL)));
    }
}

extern "C" void kernel_launch(void* const* d_in, const int* in_sizes, int n_in,
                              void* d_out, int out_size, void* d_ws, size_t ws_size,
                              hipStream_t stream) {
    const float* pred = (const float*)d_in[0];
    const float* obs  = (const float*)d_in[1];
    float* out = (float*)d_out;
    hipMemsetAsync(out, 0, sizeof(float), stream);
    wass_kernel<<<NBLOCKS, BLOCK, 0, stream>>>(pred, obs, out);
}

// Round 10
// 275.304 us; speedup vs baseline: 2.6256x; 2.6256x over previous
//
#include <hip/hip_runtime.h>

#define NT 4096          // time samples per column
#define NCOL 4096        // 512 traces * 8 channels
#define EPT 64           // elements per lane: one wave sorts one whole column
#define BLOCK 512        // 8 waves: waves 0-3 pred cols w, waves 4-7 obs cols w
#define NBLOCKS 1024     // 4096 cols / 4 cols per block

__device__ __forceinline__ float b2f(int i) { return __builtin_bit_cast(float, i); }
__device__ __forceinline__ int   f2b(float f) { return __builtin_bit_cast(int, f); }

// Cross-lane fetch of partner lane^XM's value.
// XM 1,2,3 (quad_perm), 7 (row_half_mirror), 8 (row_ror:8), 15 (row_mirror): DPP,
// VALU pipe, zero DS traffic. XM 4,16,31: ds_swizzle. XM 63: ds_bpermute.
template <int XM>
__device__ __forceinline__ float lx(float v) {
    const int i = f2b(v);
    int r;
    if constexpr (XM == 1)       r = __builtin_amdgcn_update_dpp(0, i, 0xB1,  0xF, 0xF, true);
    else if constexpr (XM == 2)  r = __builtin_amdgcn_update_dpp(0, i, 0x4E,  0xF, 0xF, true);
    else if constexpr (XM == 3)  r = __builtin_amdgcn_update_dpp(0, i, 0x1B,  0xF, 0xF, true);
    else if constexpr (XM == 7)  r = __builtin_amdgcn_update_dpp(0, i, 0x141, 0xF, 0xF, true);
    else if constexpr (XM == 8)  r = __builtin_amdgcn_update_dpp(0, i, 0x128, 0xF, 0xF, true);
    else if constexpr (XM == 15) r = __builtin_amdgcn_update_dpp(0, i, 0x140, 0xF, 0xF, true);
    else if constexpr (XM == 4)  r = __builtin_amdgcn_ds_swizzle(i, 0x101F);
    else if constexpr (XM == 16) r = __builtin_amdgcn_ds_swizzle(i, 0x401F);
    else if constexpr (XM == 31) r = __builtin_amdgcn_ds_swizzle(i, 0x7C1F);
    else {
        const int lane = (int)(threadIdx.x & 63);
        r = __builtin_amdgcn_ds_bpermute((lane ^ XM) << 2, i);
    }
    return b2f(r);
}

__device__ __forceinline__ void cemin(float& a, float& b) {
    const float lo = fminf(a, b);
    const float hi = fmaxf(a, b);
    a = lo; b = hi;
}
__device__ __forceinline__ float csel(float x, float y, bool keep_min) {
    return ((x < y) == keep_min) ? x : y;
}

// plain cross-lane stage, lane-xor M, same element index
template <int M>
__device__ __forceinline__ void plain_stage(float (&x)[EPT], int L) {
    const bool km = (L & M) == 0;
    #pragma unroll
    for (int e = 0; e < EPT; ++e) {
        const float y = lx<M>(x[e]);
        x[e] = csel(x[e], y, km);
    }
}

template <int M>
__device__ __forceinline__ void plains_down(float (&x)[EPT], int L) {
    plain_stage<M>(x, L);
    if constexpr (M > 1) plains_down<M / 2>(x, L);
}

// intra-thread plain stages j = 32..1, all ascending (normalized network)
__device__ __forceinline__ void tail32(float (&x)[EPT]) {
    #pragma unroll
    for (int j = 32; j >= 1; j >>= 1) {
        #pragma unroll
        for (int e = 0; e < EPT; ++e)
            if ((e & j) == 0) cemin(x[e], x[e | j]);
    }
}

// Normalized bitonic merge of size k = 64*K (K = 2..64), fully in-wave:
// reversal: partner lane L^(K-1), element mirror e<->63-e, keep-min if (L&K/2)==0;
// then plain lane-xor stages m=K/4..1; then intra-thread tail j=32..1.
template <int K>
__device__ __forceinline__ void cross_merge(float (&x)[EPT], int L) {
    const bool km = (L & (K >> 1)) == 0;
    #pragma unroll
    for (int e = 0; e < EPT / 2; ++e) {
        const float ylo = lx<K - 1>(x[EPT - 1 - e]);   // partner's mirrored element
        const float yhi = lx<K - 1>(x[e]);
        x[e]           = csel(x[e], ylo, km);
        x[EPT - 1 - e] = csel(x[EPT - 1 - e], yhi, km);
    }
    if constexpr (K >= 4) plains_down<K / 4>(x, L);
    tail32(x);
}

// LDS (one union, phases sequential):
//   staging: 2 halves x 4 cols x 1024-word chunk regions = 8192 words (32 KB)
//   epilogue strips: 4 cols x 64 lanes x 33 words        = 8448 words (33 KB)
#define LS_WORDS 8448

__global__ __launch_bounds__(512, 4) void wass_kernel(const float* __restrict__ pred,
                                                      const float* __restrict__ obs,
                                                      float* __restrict__ out) {
    __shared__ __align__(16) float ls[LS_WORDS];

    const int bid  = blockIdx.x;
    const int cb   = (bid & 7) * 128 + (bid >> 3);   // XCD-band col-block swizzle
    const int col0 = cb * 4;

    const int t    = threadIdx.x;
    const int half = t >> 8;           // 0 = pred, 1 = obs
    const int ht   = t & 255;          // thread within half
    const int w    = (t >> 6) & 3;     // column (0..3) this wave sorts
    const int L    = t & 63;           // lane

    const float* __restrict__ src = half ? obs : pred;

    // ---- staged load + transpose: 4 chunks of 1024 rows, one-chunk-ahead
    // register prefetch (pv[4], 16 VGPR). Loads for chunk q+1 issue right
    // after the write->read barrier of chunk q, so their HBM latency hides
    // under the 16 LDS reads + barrier + next write's address calc.
    // Per (half, col): 1024-word region, word(lr) = (lr&~31)|((lr&31)^((lr>>5)&15)).
    // Writer thread ht owns lr = 4*ht+j; reader lane L reads lr = L*16+s.
    // Both are exactly 2-way bank aliased = free.
    float x[EPT];
    {
        float* stg = ls + half * 4096;
        float4 pv[4];
        #pragma unroll
        for (int j = 0; j < 4; ++j) {
            const int lr = (ht << 2) | j;                          // 0..1023
            const int r  = (lr >> 4) * 64 + (lr & 15);             // chunk 0
            pv[j] = *(const float4*)&src[(size_t)r * NCOL + col0];
        }
        #pragma unroll
        for (int q = 0; q < 4; ++q) {
            #pragma unroll
            for (int j = 0; j < 4; ++j) {
                const int lr = (ht << 2) | j;
                const int wd = (lr & ~31) | ((lr & 31) ^ ((lr >> 5) & 15));
                stg[wd]        = pv[j].x;      // column col0
                stg[1024 + wd] = pv[j].y;      // column col0+1
                stg[2048 + wd] = pv[j].z;      // column col0+2
                stg[3072 + wd] = pv[j].w;      // column col0+3
            }
            __syncthreads();
            if (q < 3) {
                #pragma unroll
                for (int j = 0; j < 4; ++j) {
                    const int lr = (ht << 2) | j;
                    const int r  = (lr >> 4) * 64 + (q + 1) * 16 + (lr & 15);
                    pv[j] = *(const float4*)&src[(size_t)r * NCOL + col0];
                }
            }
            #pragma unroll
            for (int s = 0; s < 16; ++s) {
                const int lr = L * 16 + s;
                const int wd = (lr & ~31) | ((lr & 31) ^ ((lr >> 5) & 15));
                x[q * 16 + s] = stg[w * 1024 + wd];
            }
            __syncthreads();
        }
    }

    // ---- phase 1: normalized bitonic sort of my 64 contiguous elements ----
    #pragma unroll
    for (int k = 2; k <= 64; k <<= 1) {
        #pragma unroll
        for (int base = 0; base < EPT; base += k) {
            #pragma unroll
            for (int o = 0; o < k / 2; ++o)
                cemin(x[base + o], x[base + k - 1 - o]);
        }
        #pragma unroll
        for (int j = k / 4; j >= 1; j >>= 1) {
            #pragma unroll
            for (int e = 0; e < EPT; ++e)
                if ((e & j) == 0) cemin(x[e], x[e | j]);
        }
    }

    // ---- phase 2: merges k = 128..4096, all in-wave, no barriers ----
    cross_merge<2>(x, L);
    cross_merge<4>(x, L);
    cross_merge<8>(x, L);
    cross_merge<16>(x, L);
    cross_merge<32>(x, L);
    cross_merge<64>(x, L);

    // ---- epilogue: two 32-element passes, scalar stride-33 strips.
    // bank = (L+e)&31 for both write and read: 2-way, free. ----
    __syncthreads();                   // staging region is dead; safe to reuse
    const int sb = (w * 64 + L) * 33;
    float s = 0.0f;
    #pragma unroll
    for (int hh = 0; hh < 2; ++hh) {
        if (half == 0) {
            #pragma unroll
            for (int e = 0; e < 32; ++e)
                ls[sb + e] = x[hh * 32 + e];
        }
        __syncthreads();
        if (half == 1) {
            #pragma unroll
            for (int e = 0; e < 32; ++e)
                s += fabsf(x[hh * 32 + e] - ls[sb + e]);
        }
        __syncthreads();
    }
    if (half == 1) {
        #pragma unroll
        for (int off = 32; off > 0; off >>= 1)
            s += __shfl_down(s, off, 64);
        if (L == 0)
            atomicAdd(out, s * (1.0f / ((float)NT * (float)NCOL)));
    }
}

extern "C" void kernel_launch(void* const* d_in, const int* in_sizes, int n_in,
                              void* d_out, int out_size, void* d_ws, size_t ws_size,
                              hipStream_t stream) {
    const float* pred = (const float*)d_in[0];
    const float* obs  = (const float*)d_in[1];
    float* out = (float*)d_out;
    hipMemsetAsync(out, 0, sizeof(float), stream);
    wass_kernel<<<NBLOCKS, BLOCK, 0, stream>>>(pred, obs, out);
}

// Round 11
// 262.862 us; speedup vs baseline: 2.7499x; 1.0473x over previous
//
#include <hip/hip_runtime.h>

#define NT 4096          // time samples per column
#define NCOL 4096        // 512 traces * 8 channels
#define EPT 64           // elements per lane: one wave sorts one whole column
#define BLOCK 512        // 8 waves: waves 0-3 pred cols w, waves 4-7 obs cols w
#define NBLOCKS 1024     // 4096 cols / 4 cols per block

__device__ __forceinline__ float b2f(int i) { return __builtin_bit_cast(float, i); }
__device__ __forceinline__ int   f2b(float f) { return __builtin_bit_cast(int, f); }

// Raw workgroup barrier for the staging loop: drains LDS ops (lgkmcnt) but
// leaves global loads (vmcnt) IN FLIGHT across the barrier — unlike
// __syncthreads(), which hipcc lowers to a full vmcnt(0) drain and which
// defeated R10's prefetch. "memory" clobber orders the surrounding ds ops.
__device__ __forceinline__ void barrier_keep_vmcnt() {
    asm volatile("s_waitcnt lgkmcnt(0)\n\ts_barrier" ::: "memory");
}

// Cross-lane fetch of partner lane^XM's value.
// XM 1,2,3 (quad_perm), 7 (row_half_mirror), 8 (row_ror:8), 15 (row_mirror): DPP,
// VALU pipe, zero DS traffic. XM 4,16,31: ds_swizzle. XM 63: ds_bpermute.
template <int XM>
__device__ __forceinline__ float lx(float v) {
    const int i = f2b(v);
    int r;
    if constexpr (XM == 1)       r = __builtin_amdgcn_update_dpp(0, i, 0xB1,  0xF, 0xF, true);
    else if constexpr (XM == 2)  r = __builtin_amdgcn_update_dpp(0, i, 0x4E,  0xF, 0xF, true);
    else if constexpr (XM == 3)  r = __builtin_amdgcn_update_dpp(0, i, 0x1B,  0xF, 0xF, true);
    else if constexpr (XM == 7)  r = __builtin_amdgcn_update_dpp(0, i, 0x141, 0xF, 0xF, true);
    else if constexpr (XM == 8)  r = __builtin_amdgcn_update_dpp(0, i, 0x128, 0xF, 0xF, true);
    else if constexpr (XM == 15) r = __builtin_amdgcn_update_dpp(0, i, 0x140, 0xF, 0xF, true);
    else if constexpr (XM == 4)  r = __builtin_amdgcn_ds_swizzle(i, 0x101F);
    else if constexpr (XM == 16) r = __builtin_amdgcn_ds_swizzle(i, 0x401F);
    else if constexpr (XM == 31) r = __builtin_amdgcn_ds_swizzle(i, 0x7C1F);
    else {
        const int lane = (int)(threadIdx.x & 63);
        r = __builtin_amdgcn_ds_bpermute((lane ^ XM) << 2, i);
    }
    return b2f(r);
}

__device__ __forceinline__ void cemin(float& a, float& b) {
    const float lo = fminf(a, b);
    const float hi = fmaxf(a, b);
    a = lo; b = hi;
}
__device__ __forceinline__ float csel(float x, float y, bool keep_min) {
    return ((x < y) == keep_min) ? x : y;
}

// plain cross-lane stage, lane-xor M, same element index
template <int M>
__device__ __forceinline__ void plain_stage(float (&x)[EPT], int L) {
    const bool km = (L & M) == 0;
    #pragma unroll
    for (int e = 0; e < EPT; ++e) {
        const float y = lx<M>(x[e]);
        x[e] = csel(x[e], y, km);
    }
}

template <int M>
__device__ __forceinline__ void plains_down(float (&x)[EPT], int L) {
    plain_stage<M>(x, L);
    if constexpr (M > 1) plains_down<M / 2>(x, L);
}

// intra-thread plain stages j = 32..1, all ascending (normalized network)
__device__ __forceinline__ void tail32(float (&x)[EPT]) {
    #pragma unroll
    for (int j = 32; j >= 1; j >>= 1) {
        #pragma unroll
        for (int e = 0; e < EPT; ++e)
            if ((e & j) == 0) cemin(x[e], x[e | j]);
    }
}

// Normalized bitonic merge of size k = 64*K (K = 2..64), fully in-wave:
// reversal: partner lane L^(K-1), element mirror e<->63-e, keep-min if (L&K/2)==0;
// then plain lane-xor stages m=K/4..1; then intra-thread tail j=32..1.
template <int K>
__device__ __forceinline__ void cross_merge(float (&x)[EPT], int L) {
    const bool km = (L & (K >> 1)) == 0;
    #pragma unroll
    for (int e = 0; e < EPT / 2; ++e) {
        const float ylo = lx<K - 1>(x[EPT - 1 - e]);   // partner's mirrored element
        const float yhi = lx<K - 1>(x[e]);
        x[e]           = csel(x[e], ylo, km);
        x[EPT - 1 - e] = csel(x[EPT - 1 - e], yhi, km);
    }
    if constexpr (K >= 4) plains_down<K / 4>(x, L);
    tail32(x);
}

// LDS (one union, phases sequential):
//   staging: 2 halves x 4 cols x 1024-word chunk regions = 8192 words (32 KB)
//   epilogue strips: 4 cols x 64 lanes x 33 words        = 8448 words (33 KB)
#define LS_WORDS 8448

__global__ __launch_bounds__(512, 4) void wass_kernel(const float* __restrict__ pred,
                                                      const float* __restrict__ obs,
                                                      float* __restrict__ out) {
    __shared__ __align__(16) float ls[LS_WORDS];

    const int bid  = blockIdx.x;
    const int cb   = (bid & 7) * 128 + (bid >> 3);   // XCD-band col-block swizzle
    const int col0 = cb * 4;

    const int t    = threadIdx.x;
    const int half = t >> 8;           // 0 = pred, 1 = obs
    const int ht   = t & 255;          // thread within half
    const int w    = (t >> 6) & 3;     // column (0..3) this wave sorts
    const int L    = t & 63;           // lane

    const float* __restrict__ src = half ? obs : pred;

    // ---- staged load + transpose: 4 chunks of 1024 rows, one-chunk-ahead
    // register prefetch + vmcnt-preserving barriers. Loads for chunk q+1
    // issue right after the write->read barrier of chunk q and REMAIN IN
    // FLIGHT across both raw barriers; their HBM latency hides under the 16
    // ds_reads + barrier. The compiler's automatic counted vmcnt wait lands
    // just before the ds_writes that consume them.
    // Per (half, col): 1024-word region, word(lr) = (lr&~31)|((lr&31)^((lr>>5)&15)).
    // Writer thread ht owns lr = 4*ht+j; reader lane L reads lr = L*16+s.
    // Both are exactly 2-way bank aliased = free.
    float x[EPT];
    {
        float* stg = ls + half * 4096;
        float4 pv[4];
        #pragma unroll
        for (int j = 0; j < 4; ++j) {
            const int lr = (ht << 2) | j;                          // 0..1023
            const int r  = (lr >> 4) * 64 + (lr & 15);             // chunk 0
            pv[j] = *(const float4*)&src[(size_t)r * NCOL + col0];
        }
        #pragma unroll
        for (int q = 0; q < 4; ++q) {
            #pragma unroll
            for (int j = 0; j < 4; ++j) {
                const int lr = (ht << 2) | j;
                const int wd = (lr & ~31) | ((lr & 31) ^ ((lr >> 5) & 15));
                stg[wd]        = pv[j].x;      // column col0
                stg[1024 + wd] = pv[j].y;      // column col0+1
                stg[2048 + wd] = pv[j].z;      // column col0+2
                stg[3072 + wd] = pv[j].w;      // column col0+3
            }
            barrier_keep_vmcnt();              // writes visible; vmcnt NOT drained
            if (q < 3) {
                #pragma unroll
                for (int j = 0; j < 4; ++j) {
                    const int lr = (ht << 2) | j;
                    const int r  = (lr >> 4) * 64 + (q + 1) * 16 + (lr & 15);
                    pv[j] = *(const float4*)&src[(size_t)r * NCOL + col0];
                }
            }
            #pragma unroll
            for (int s = 0; s < 16; ++s) {
                const int lr = L * 16 + s;
                const int wd = (lr & ~31) | ((lr & 31) ^ ((lr >> 5) & 15));
                x[q * 16 + s] = stg[w * 1024 + wd];
            }
            barrier_keep_vmcnt();              // reads done; prefetch still in flight
        }
    }

    // ---- phase 1: normalized bitonic sort of my 64 contiguous elements ----
    #pragma unroll
    for (int k = 2; k <= 64; k <<= 1) {
        #pragma unroll
        for (int base = 0; base < EPT; base += k) {
            #pragma unroll
            for (int o = 0; o < k / 2; ++o)
                cemin(x[base + o], x[base + k - 1 - o]);
        }
        #pragma unroll
        for (int j = k / 4; j >= 1; j >>= 1) {
            #pragma unroll
            for (int e = 0; e < EPT; ++e)
                if ((e & j) == 0) cemin(x[e], x[e | j]);
        }
    }

    // ---- phase 2: merges k = 128..4096, all in-wave, no barriers ----
    cross_merge<2>(x, L);
    cross_merge<4>(x, L);
    cross_merge<8>(x, L);
    cross_merge<16>(x, L);
    cross_merge<32>(x, L);
    cross_merge<64>(x, L);

    // ---- epilogue: two 32-element passes, scalar stride-33 strips.
    // bank = (L+e)&31 for both write and read: 2-way, free. ----
    __syncthreads();                   // staging region is dead; safe to reuse
    const int sb = (w * 64 + L) * 33;
    float s = 0.0f;
    #pragma unroll
    for (int hh = 0; hh < 2; ++hh) {
        if (half == 0) {
            #pragma unroll
            for (int e = 0; e < 32; ++e)
                ls[sb + e] = x[hh * 32 + e];
        }
        __syncthreads();
        if (half == 1) {
            #pragma unroll
            for (int e = 0; e < 32; ++e)
                s += fabsf(x[hh * 32 + e] - ls[sb + e]);
        }
        __syncthreads();
    }
    if (half == 1) {
        #pragma unroll
        for (int off = 32; off > 0; off >>= 1)
            s += __shfl_down(s, off, 64);
        if (L == 0)
            atomicAdd(out, s * (1.0f / ((float)NT * (float)NCOL)));
    }
}

extern "C" void kernel_launch(void* const* d_in, const int* in_sizes, int n_in,
                              void* d_out, int out_size, void* d_ws, size_t ws_size,
                              hipStream_t stream) {
    const float* pred = (const float*)d_in[0];
    const float* obs  = (const float*)d_in[1];
    float* out = (float*)d_out;
    hipMemsetAsync(out, 0, sizeof(float), stream);
    wass_kernel<<<NBLOCKS, BLOCK, 0, stream>>>(pred, obs, out);
}